// Round 8
// baseline (241.670 us; speedup 1.0000x reference)
//
#include <hip/hip_runtime.h>
#include <hip/hip_bf16.h>

// RNN-T joiner: out[b,t,u,v] = sum_k relu(x[b,t,k]+y[b,u,k]) * W[v,k] + bias[v]
// GEMM: M=131072, N=1024, K=512; A generated on the fly.
//
// v7 = v6 structure (barrier-free k-loop, W->registers from L2, A-only LDS)
// with wave tile 128x64 (4 m16 x 2 n16): W L2 traffic halves (2.1->1.05 GB),
// putting MFMA issue (1024 cy/step/CU) above W-stream (~585 cy) and LDS
// (~512 cy). BM=128 (2 t x 64 u), BN=512, 8 waves, A full-K in 128 KB LDS,
// 1 block/CU, ~2 waves/SIMD (acc=128 VGPR). Epilogue: per-wave LDS transpose
// overlaid on As -> f32x4 nontemporal full-128B-line stores.

constexpr int Bc = 8, Tc = 256, Uc = 64, Dc = 512, Vc = 1024;
constexpr int BM = 128, BN = 512;
constexpr int NSTEPS = 16;   // K=512 in steps of 32
constexpr int BDIM = 512;    // 8 waves, side by side in n

typedef __attribute__((ext_vector_type(8)))  short short8;
typedef __attribute__((ext_vector_type(8)))  unsigned short ushort8;
typedef __attribute__((ext_vector_type(4)))  float f32x4;
typedef __attribute__((ext_vector_type(16))) float f32x16;

__device__ inline unsigned short f2bf(float f) {
    union { float f; unsigned u; } v; v.f = f;
    unsigned r = v.u + 0x7FFFu + ((v.u >> 16) & 1u);  // RNE
    return (unsigned short)(r >> 16);
}

// ---- prep: W fp32 [V][D] -> bf16 chunk layout Wt[(koct>>1)*2048 + v*2 + (koct&1)]
// (16B chunks; koct = k/8). A wave's B-frag load = 1KB contiguous.
__global__ __launch_bounds__(256) void cvt_wt(const float* __restrict__ W,
                                              unsigned short* __restrict__ Wt) {
    const int idx  = blockIdx.x * 256 + threadIdx.x;  // 65536 total
    const int v    = idx >> 6;
    const int koct = idx & 63;
    const float4 a = *(const float4*)(W + (size_t)v * Dc + koct * 8);
    const float4 b = *(const float4*)(W + (size_t)v * Dc + koct * 8 + 4);
    ushort8 o;
    o[0] = f2bf(a.x); o[1] = f2bf(a.y); o[2] = f2bf(a.z); o[3] = f2bf(a.w);
    o[4] = f2bf(b.x); o[5] = f2bf(b.y); o[6] = f2bf(b.z); o[7] = f2bf(b.w);
    const size_t chunk = (size_t)(koct >> 1) * 2048 + v * 2 + (koct & 1);
    *(ushort8*)(Wt + chunk * 8) = o;
}

__global__ __launch_bounds__(BDIM, 2) void joiner_v7(
    const float* __restrict__ x, const float* __restrict__ y,
    const unsigned short* __restrict__ Wt, const float* __restrict__ bias,
    float* __restrict__ out)
{
    __shared__ __align__(16) unsigned char smem[BM * Dc * 2];  // 128 KB
    unsigned short* As = (unsigned short*)smem;                 // k-loop use
    // epilogue overlays per-wave transpose pads on the same memory

    const int tid  = threadIdx.x;
    const int lane = tid & 63;
    const int wid  = tid >> 6;        // 0..7, n-position
    const int l31  = lane & 31;
    const int l32  = lane >> 5;       // 0/1

    const int nhalf = blockIdx.x & 1;
    const int mb    = blockIdx.x >> 1;       // 0..1023
    const int bb    = mb >> 7;               // batch (128 m-tiles per batch)
    const int t0    = (mb & 127) * 2;        // rows cover t0, t0+1 (u = r&63)
    const int m0    = mb * BM;
    const int n0    = nhalf * BN;
    const int colbase = n0 + wid * 64;

    float bv[2];
    bv[0] = bias[colbase + l31];
    bv[1] = bias[colbase + 32 + l31];

    // ---- stage A = relu(x[b,t,:]+y[b,u,:]) bf16, XOR-swizzled ----
    const float* xrow0 = x + (size_t)(bb * Tc + t0) * Dc;
    #pragma unroll
    for (int i = 0; i < 16; ++i) {
        const int c = tid + i * BDIM;       // 0..8191
        const int r = c >> 6;               // row 0..127
        const int s = c & 63;               // k-octet
        const float4* xp = (const float4*)(xrow0 + (size_t)(r >> 6) * Dc + s * 8);
        const float4* yp = (const float4*)(y + ((size_t)(bb * Uc + (r & 63)) * Dc + s * 8));
        float4 xa = xp[0], xb = xp[1];
        float4 ya = yp[0], yb = yp[1];
        ushort8 hv;
        hv[0] = f2bf(fmaxf(xa.x + ya.x, 0.f));
        hv[1] = f2bf(fmaxf(xa.y + ya.y, 0.f));
        hv[2] = f2bf(fmaxf(xa.z + ya.z, 0.f));
        hv[3] = f2bf(fmaxf(xa.w + ya.w, 0.f));
        hv[4] = f2bf(fmaxf(xb.x + yb.x, 0.f));
        hv[5] = f2bf(fmaxf(xb.y + yb.y, 0.f));
        hv[6] = f2bf(fmaxf(xb.z + yb.z, 0.f));
        hv[7] = f2bf(fmaxf(xb.w + yb.w, 0.f));
        *(ushort8*)(&As[r * Dc + ((s ^ (r & 7)) * 8)]) = hv;
    }
    __syncthreads();

    // ---- W frag base: chunk (ks*2+q)*2048 + col*2 + l32 ----
    const unsigned short* pW = Wt + (size_t)(colbase * 2 + 2 * l31 + l32) * 8;

    f32x16 acc[4][2] = {};        // [m16][n16] 32x32 sub-tiles (128 VGPR)
    short8 wfA[2][2], wfB[2][2];  // [q][n16] named double-buffer

    #define LOADW(buf, ks)                                                    \
        {                                                                     \
            _Pragma("unroll")                                                 \
            for (int q = 0; q < 2; ++q)                                       \
                _Pragma("unroll")                                             \
                for (int n16 = 0; n16 < 2; ++n16)                             \
                    buf[q][n16] = *(const short8*)(pW + ((ks) * 2 + q) * 16384 \
                                                   + n16 * 512);              \
        }

    #define STEP(cur, nxt, ks)                                                \
        {                                                                     \
            if ((ks) + 1 < NSTEPS) LOADW(nxt, (ks) + 1);                      \
            _Pragma("unroll")                                                 \
            for (int q = 0; q < 2; ++q) {                                     \
                const int oA = (ks) * 4 + q * 2 + l32;                        \
                short8 af[4];                                                 \
                _Pragma("unroll")                                             \
                for (int m16 = 0; m16 < 4; ++m16)                             \
                    af[m16] = *(const short8*)(&As[(m16 * 32 + l31) * Dc      \
                                               + ((oA ^ (l31 & 7)) * 8)]);    \
                __builtin_amdgcn_s_setprio(1);                                \
                _Pragma("unroll")                                             \
                for (int m16 = 0; m16 < 4; ++m16) {                           \
                    acc[m16][0] = __builtin_amdgcn_mfma_f32_32x32x16_bf16(    \
                        af[m16], cur[q][0], acc[m16][0], 0, 0, 0);            \
                    acc[m16][1] = __builtin_amdgcn_mfma_f32_32x32x16_bf16(    \
                        af[m16], cur[q][1], acc[m16][1], 0, 0, 0);            \
                }                                                             \
                __builtin_amdgcn_s_setprio(0);                                \
            }                                                                 \
        }

    LOADW(wfA, 0);
    #pragma unroll
    for (int ks = 0; ks < NSTEPS; ks += 2) {
        STEP(wfA, wfB, ks);
        STEP(wfB, wfA, ks + 1);
    }
    #undef STEP
    #undef LOADW

    // ---- epilogue: overlay Tr on As space (all A reads done) ----
    __syncthreads();
    float* tr = (float*)smem + wid * (16 * 36);  // 2.3KB per wave
    #pragma unroll
    for (int m16 = 0; m16 < 4; ++m16) {
        #pragma unroll
        for (int n16 = 0; n16 < 2; ++n16) {
            #pragma unroll
            for (int h = 0; h < 2; ++h) {   // regs h*8..h*8+7 -> rows h*16..+15
                #pragma unroll
                for (int e = 0; e < 8; ++e) {
                    const int rl = (e & 3) + 8 * (e >> 2) + 4 * l32;  // 0..15
                    tr[rl * 36 + l31] = acc[m16][n16][h * 8 + e] + bv[n16];
                }
                #pragma unroll
                for (int h2 = 0; h2 < 2; ++h2) {
                    const int rr = h2 * 8 + (lane >> 3);   // 0..15
                    const int c4 = (lane & 7) * 4;         // 0..28
                    f32x4 o;
                    o[0] = tr[rr * 36 + c4 + 0];
                    o[1] = tr[rr * 36 + c4 + 1];
                    o[2] = tr[rr * 36 + c4 + 2];
                    o[3] = tr[rr * 36 + c4 + 3];
                    const size_t off =
                        (size_t)(m0 + m16 * 32 + h * 16 + rr) * Vc
                        + colbase + n16 * 32 + c4;
                    __builtin_nontemporal_store(o, (f32x4*)(out + off));
                }
            }
        }
    }
}

// ---- round-1 fallback (only if ws_size < 1MB) ----
constexpr int F_BM = 128, F_BN = 128, F_BK = 64;
constexpr int F_MT = (Bc * Tc * Uc) / F_BM;
constexpr int F_NT = Vc / F_BN;

__global__ __launch_bounds__(256) void joiner_mfma(
    const float* __restrict__ x, const float* __restrict__ y,
    const float* __restrict__ W, const float* __restrict__ bias,
    float* __restrict__ out)
{
    __shared__ unsigned short As[F_BM * F_BK];
    __shared__ unsigned short Wsh[F_BN * F_BK];
    const int tid = threadIdx.x;
    const int mtile = blockIdx.x % F_MT;
    const int ntile = blockIdx.x / F_MT;
    const int m0 = mtile * F_BM, v0 = ntile * F_BN;
    const int bb = m0 / (Tc * Uc);
    const int t0 = (m0 % (Tc * Uc)) / Uc;
    const int lane = tid & 63, wid = tid >> 6;
    const int wm = wid >> 1, wn = wid & 1;
    const int lr = lane & 15, lk8 = lane >> 4;
    f32x4 acc[4][4] = {};
    for (int k0 = 0; k0 < Dc; k0 += F_BK) {
        __syncthreads();
        #pragma unroll
        for (int i = 0; i < 4; ++i) {
            const int chunk = tid + i * 256;
            const int row = chunk >> 3, slot = chunk & 7;
            const int ps8 = (slot ^ (row & 7)) * 8;
            const int t = t0 + (row >> 6), u = row & 63;
            const float4* xp = (const float4*)(x + ((size_t)(bb * Tc + t) * Dc + k0 + slot * 8));
            const float4* yp = (const float4*)(y + ((size_t)(bb * Uc + u) * Dc + k0 + slot * 8));
            float4 xa = xp[0], xb2 = xp[1], ya = yp[0], yb2 = yp[1];
            ushort8 hv;
            hv[0] = f2bf(fmaxf(xa.x + ya.x, 0.f)); hv[1] = f2bf(fmaxf(xa.y + ya.y, 0.f));
            hv[2] = f2bf(fmaxf(xa.z + ya.z, 0.f)); hv[3] = f2bf(fmaxf(xa.w + ya.w, 0.f));
            hv[4] = f2bf(fmaxf(xb2.x + yb2.x, 0.f)); hv[5] = f2bf(fmaxf(xb2.y + yb2.y, 0.f));
            hv[6] = f2bf(fmaxf(xb2.z + yb2.z, 0.f)); hv[7] = f2bf(fmaxf(xb2.w + yb2.w, 0.f));
            *(ushort8*)(&As[row * F_BK + ps8]) = hv;
            const float4* wp = (const float4*)(W + ((size_t)(v0 + row) * Dc + k0 + slot * 8));
            float4 wa = wp[0], wb2 = wp[1];
            ushort8 wv;
            wv[0] = f2bf(wa.x); wv[1] = f2bf(wa.y); wv[2] = f2bf(wa.z); wv[3] = f2bf(wa.w);
            wv[4] = f2bf(wb2.x); wv[5] = f2bf(wb2.y); wv[6] = f2bf(wb2.z); wv[7] = f2bf(wb2.w);
            *(ushort8*)(&Wsh[row * F_BK + ps8]) = wv;
        }
        __syncthreads();
        #pragma unroll
        for (int kk = 0; kk < 2; ++kk) {
            const int psk = kk * 4 + lk8;
            short8 af[4], bfr[4];
            #pragma unroll
            for (int mf = 0; mf < 4; ++mf) {
                const int row = wm * 64 + mf * 16 + lr;
                af[mf] = *(const short8*)(&As[row * F_BK + ((psk ^ (row & 7)) * 8)]);
            }
            #pragma unroll
            for (int nf = 0; nf < 4; ++nf) {
                const int row = wn * 64 + nf * 16 + lr;
                bfr[nf] = *(const short8*)(&Wsh[row * F_BK + ((psk ^ (row & 7)) * 8)]);
            }
            #pragma unroll
            for (int mf = 0; mf < 4; ++mf)
                #pragma unroll
                for (int nf = 0; nf < 4; ++nf)
                    acc[mf][nf] = __builtin_amdgcn_mfma_f32_16x16x32_bf16(af[mf], bfr[nf], acc[mf][nf], 0, 0, 0);
        }
    }
    #pragma unroll
    for (int nf = 0; nf < 4; ++nf) {
        const int v = v0 + wn * 64 + nf * 16 + lr;
        const float bv = bias[v];
        #pragma unroll
        for (int mf = 0; mf < 4; ++mf) {
            const int mrow = m0 + wm * 64 + mf * 16 + (lane >> 4) * 4;
            #pragma unroll
            for (int j = 0; j < 4; ++j)
                out[(size_t)(mrow + j) * Vc + v] = acc[mf][nf][j] + bv;
        }
    }
}

extern "C" void kernel_launch(void* const* d_in, const int* in_sizes, int n_in,
                              void* d_out, int out_size, void* d_ws, size_t ws_size,
                              hipStream_t stream) {
    const float* x = (const float*)d_in[0];
    const float* y = (const float*)d_in[1];
    const float* W = (const float*)d_in[2];
    const float* b = (const float*)d_in[3];
    float* out = (float*)d_out;

    const size_t w_bytes = (size_t)Vc * Dc * sizeof(unsigned short);  // 1 MB
    if (ws_size >= w_bytes) {
        unsigned short* Wt = (unsigned short*)d_ws;
        cvt_wt<<<dim3((Vc * Dc / 8) / 256), 256, 0, stream>>>(W, Wt);
        joiner_v7<<<dim3((Bc * Tc * Uc / BM) * (Vc / BN)), BDIM, 0, stream>>>(x, y, Wt, b, out);
    } else {
        joiner_mfma<<<dim3(F_MT * F_NT), 256, 0, stream>>>(x, y, W, b, out);
    }
}

// Round 9
// 185.281 us; speedup vs baseline: 1.3043x; 1.3043x over previous
//
#include <hip/hip_runtime.h>
#include <hip/hip_bf16.h>

// RNN-T joiner: out[b,t,u,v] = sum_k relu(x[b,t,k]+y[b,u,k]) * W[v,k] + bias[v]
// GEMM: M=131072, N=1024, K=512; A generated on the fly.
//
// v8 = v6 (best: 201us; barrier-free k-loop, W->regs from L2, A-only 64KB LDS,
// 2 blocks/CU, wave tile 64x64 mfma_32x32x16) + :
//  1) block remap nhalf=blockIdx>>11: co-resident blocks share the same W
//     stream (L1/L2-hot) -> W L2 traffic per CU ~halves.
//  2) A-staging packs bf16 via v_cvt_pk_bf16_f32 (RNE, 2 elems/inst).
//  3) first W prefetch issued before staging (latency hidden under staging).

constexpr int Bc = 8, Tc = 256, Uc = 64, Dc = 512, Vc = 1024;
constexpr int BM = 64, BN = 512;
constexpr int NSTEPS = 16;   // K=512 in steps of 32
constexpr int BDIM = 512;    // 8 waves, side by side in n

typedef __attribute__((ext_vector_type(8)))  short short8;
typedef __attribute__((ext_vector_type(8)))  unsigned short ushort8;
typedef __attribute__((ext_vector_type(4)))  float f32x4;
typedef __attribute__((ext_vector_type(16))) float f32x16;
typedef __attribute__((ext_vector_type(4)))  unsigned int u32x4;

__device__ inline unsigned short f2bf(float f) {
    union { float f; unsigned u; } v; v.f = f;
    unsigned r = v.u + 0x7FFFu + ((v.u >> 16) & 1u);  // RNE
    return (unsigned short)(r >> 16);
}

__device__ inline unsigned int pkbf(float lo, float hi) {
    unsigned int r;
    asm("v_cvt_pk_bf16_f32 %0, %1, %2" : "=v"(r) : "v"(lo), "v"(hi));
    return r;  // lo word = cvt(lo), hi word = cvt(hi), RNE
}

// ---- prep: W fp32 [V][D] -> bf16 chunk layout Wt[(koct>>1)*2048 + v*2 + (koct&1)]
__global__ __launch_bounds__(256) void cvt_wt(const float* __restrict__ W,
                                              unsigned short* __restrict__ Wt) {
    const int idx  = blockIdx.x * 256 + threadIdx.x;  // 65536 total
    const int v    = idx >> 6;
    const int koct = idx & 63;
    const float4 a = *(const float4*)(W + (size_t)v * Dc + koct * 8);
    const float4 b = *(const float4*)(W + (size_t)v * Dc + koct * 8 + 4);
    ushort8 o;
    o[0] = f2bf(a.x); o[1] = f2bf(a.y); o[2] = f2bf(a.z); o[3] = f2bf(a.w);
    o[4] = f2bf(b.x); o[5] = f2bf(b.y); o[6] = f2bf(b.z); o[7] = f2bf(b.w);
    const size_t chunk = (size_t)(koct >> 1) * 2048 + v * 2 + (koct & 1);
    *(ushort8*)(Wt + chunk * 8) = o;
}

__global__ __launch_bounds__(BDIM, 4) void joiner_v8(
    const float* __restrict__ x, const float* __restrict__ y,
    const unsigned short* __restrict__ Wt, const float* __restrict__ bias,
    float* __restrict__ out)
{
    __shared__ __align__(16) unsigned char smem[BM * Dc * 2];  // 64 KB
    unsigned short* As = (unsigned short*)smem;

    const int tid  = threadIdx.x;
    const int lane = tid & 63;
    const int wid  = tid >> 6;        // 0..7, n-position
    const int l31  = lane & 31;
    const int l32  = lane >> 5;       // 0/1

    // co-resident blocks (~256 apart) share nhalf -> shared W stream
    const int nhalf = blockIdx.x >> 11;      // grid = 4096
    const int mb    = blockIdx.x & 2047;
    const int bb    = mb >> 8;               // batch
    const int tt    = mb & 255;              // time step
    const int m0    = mb * BM;
    const int n0    = nhalf * BN;
    const int colbase = n0 + wid * 64;

    float bv[2];
    bv[0] = bias[colbase + l31];
    bv[1] = bias[colbase + 32 + l31];

    // ---- W frag base: chunk (ks*2+q)*2048 + col*2 + l32 ----
    const unsigned short* pW = Wt + (size_t)(colbase * 2 + 2 * l31 + l32) * 8;

    short8 wfA[2][2], wfB[2][2];  // [q][n16] named double-buffer

    #define LOADW(buf, ks)                                                    \
        {                                                                     \
            _Pragma("unroll")                                                 \
            for (int q = 0; q < 2; ++q)                                       \
                _Pragma("unroll")                                             \
                for (int n16 = 0; n16 < 2; ++n16)                             \
                    buf[q][n16] = *(const short8*)(pW + ((ks) * 2 + q) * 16384 \
                                                   + n16 * 512);              \
        }

    LOADW(wfA, 0);   // issued before staging: latency hidden under stage phase

    // ---- stage A = relu(x[b,t,:]+y[b,u,:]) bf16 via cvt_pk, XOR-swizzled ----
    const float* xrow = x + (size_t)(bb * Tc + tt) * Dc;
    #pragma unroll
    for (int i = 0; i < 8; ++i) {
        const int c = tid + i * BDIM;
        const int u = c >> 6;
        const int s = c & 63;
        const float4* xp = (const float4*)(xrow + s * 8);
        const float4* yp = (const float4*)(y + ((size_t)(bb * Uc + u) * Dc + s * 8));
        float4 xa = xp[0], xb = xp[1];
        float4 ya = yp[0], yb = yp[1];
        u32x4 pv;
        pv[0] = pkbf(fmaxf(xa.x + ya.x, 0.f), fmaxf(xa.y + ya.y, 0.f));
        pv[1] = pkbf(fmaxf(xa.z + ya.z, 0.f), fmaxf(xa.w + ya.w, 0.f));
        pv[2] = pkbf(fmaxf(xb.x + yb.x, 0.f), fmaxf(xb.y + yb.y, 0.f));
        pv[3] = pkbf(fmaxf(xb.z + yb.z, 0.f), fmaxf(xb.w + yb.w, 0.f));
        *(u32x4*)(&As[u * Dc + ((s ^ (u & 7)) * 8)]) = pv;
    }
    __syncthreads();

    f32x16 acc[2][2] = {};  // [m16][n16] 32x32 sub-tiles

    #define STEP(cur, nxt, ks)                                                \
        {                                                                     \
            if ((ks) + 1 < NSTEPS) LOADW(nxt, (ks) + 1);                      \
            _Pragma("unroll")                                                 \
            for (int q = 0; q < 2; ++q) {                                     \
                const int oA = (ks) * 4 + q * 2 + l32;                        \
                short8 af0 = *(const short8*)(&As[l31 * Dc                    \
                                              + ((oA ^ (l31 & 7)) * 8)]);     \
                short8 af1 = *(const short8*)(&As[(32 + l31) * Dc             \
                                              + ((oA ^ (l31 & 7)) * 8)]);     \
                __builtin_amdgcn_s_setprio(1);                                \
                acc[0][0] = __builtin_amdgcn_mfma_f32_32x32x16_bf16(          \
                    af0, cur[q][0], acc[0][0], 0, 0, 0);                      \
                acc[0][1] = __builtin_amdgcn_mfma_f32_32x32x16_bf16(          \
                    af0, cur[q][1], acc[0][1], 0, 0, 0);                      \
                acc[1][0] = __builtin_amdgcn_mfma_f32_32x32x16_bf16(          \
                    af1, cur[q][0], acc[1][0], 0, 0, 0);                      \
                acc[1][1] = __builtin_amdgcn_mfma_f32_32x32x16_bf16(          \
                    af1, cur[q][1], acc[1][1], 0, 0, 0);                      \
                __builtin_amdgcn_s_setprio(0);                                \
            }                                                                 \
        }

    #pragma unroll
    for (int ks = 0; ks < NSTEPS; ks += 2) {
        STEP(wfA, wfB, ks);
        STEP(wfB, wfA, ks + 1);
    }
    #undef STEP
    #undef LOADW

    // ---- epilogue: overlay Tr on As space (all A reads done) ----
    __syncthreads();
    float* tr = (float*)smem + wid * (16 * 36);  // 2.3KB per wave
    #pragma unroll
    for (int m16 = 0; m16 < 2; ++m16) {
        #pragma unroll
        for (int n16 = 0; n16 < 2; ++n16) {
            #pragma unroll
            for (int h = 0; h < 2; ++h) {   // regs h*8..h*8+7 -> rows h*16..+15
                #pragma unroll
                for (int e = 0; e < 8; ++e) {
                    const int rl = (e & 3) + 8 * (e >> 2) + 4 * l32;  // 0..15
                    tr[rl * 36 + l31] = acc[m16][n16][h * 8 + e] + bv[n16];
                }
                #pragma unroll
                for (int h2 = 0; h2 < 2; ++h2) {
                    const int rr = h2 * 8 + (lane >> 3);   // 0..15
                    const int c4 = (lane & 7) * 4;         // 0..28
                    f32x4 o;
                    o[0] = tr[rr * 36 + c4 + 0];
                    o[1] = tr[rr * 36 + c4 + 1];
                    o[2] = tr[rr * 36 + c4 + 2];
                    o[3] = tr[rr * 36 + c4 + 3];
                    const size_t off =
                        (size_t)(m0 + m16 * 32 + h * 16 + rr) * Vc
                        + colbase + n16 * 32 + c4;
                    __builtin_nontemporal_store(o, (f32x4*)(out + off));
                }
            }
        }
    }
}

// ---- round-1 fallback (only if ws_size < 1MB) ----
constexpr int F_BM = 128, F_BN = 128, F_BK = 64;
constexpr int F_MT = (Bc * Tc * Uc) / F_BM;
constexpr int F_NT = Vc / F_BN;

__global__ __launch_bounds__(256) void joiner_mfma(
    const float* __restrict__ x, const float* __restrict__ y,
    const float* __restrict__ W, const float* __restrict__ bias,
    float* __restrict__ out)
{
    __shared__ unsigned short As[F_BM * F_BK];
    __shared__ unsigned short Wsh[F_BN * F_BK];
    const int tid = threadIdx.x;
    const int mtile = blockIdx.x % F_MT;
    const int ntile = blockIdx.x / F_MT;
    const int m0 = mtile * F_BM, v0 = ntile * F_BN;
    const int bb = m0 / (Tc * Uc);
    const int t0 = (m0 % (Tc * Uc)) / Uc;
    const int lane = tid & 63, wid = tid >> 6;
    const int wm = wid >> 1, wn = wid & 1;
    const int lr = lane & 15, lk8 = lane >> 4;
    f32x4 acc[4][4] = {};
    for (int k0 = 0; k0 < Dc; k0 += F_BK) {
        __syncthreads();
        #pragma unroll
        for (int i = 0; i < 4; ++i) {
            const int chunk = tid + i * 256;
            const int row = chunk >> 3, slot = chunk & 7;
            const int ps8 = (slot ^ (row & 7)) * 8;
            const int t = t0 + (row >> 6), u = row & 63;
            const float4* xp = (const float4*)(x + ((size_t)(bb * Tc + t) * Dc + k0 + slot * 8));
            const float4* yp = (const float4*)(y + ((size_t)(bb * Uc + u) * Dc + k0 + slot * 8));
            float4 xa = xp[0], xb2 = xp[1], ya = yp[0], yb2 = yp[1];
            ushort8 hv;
            hv[0] = f2bf(fmaxf(xa.x + ya.x, 0.f)); hv[1] = f2bf(fmaxf(xa.y + ya.y, 0.f));
            hv[2] = f2bf(fmaxf(xa.z + ya.z, 0.f)); hv[3] = f2bf(fmaxf(xa.w + ya.w, 0.f));
            hv[4] = f2bf(fmaxf(xb2.x + yb2.x, 0.f)); hv[5] = f2bf(fmaxf(xb2.y + yb2.y, 0.f));
            hv[6] = f2bf(fmaxf(xb2.z + yb2.z, 0.f)); hv[7] = f2bf(fmaxf(xb2.w + yb2.w, 0.f));
            *(ushort8*)(&As[row * F_BK + ps8]) = hv;
            const float4* wp = (const float4*)(W + ((size_t)(v0 + row) * Dc + k0 + slot * 8));
            float4 wa = wp[0], wb2 = wp[1];
            ushort8 wv;
            wv[0] = f2bf(wa.x); wv[1] = f2bf(wa.y); wv[2] = f2bf(wa.z); wv[3] = f2bf(wa.w);
            wv[4] = f2bf(wb2.x); wv[5] = f2bf(wb2.y); wv[6] = f2bf(wb2.z); wv[7] = f2bf(wb2.w);
            *(ushort8*)(&Wsh[row * F_BK + ps8]) = wv;
        }
        __syncthreads();
        #pragma unroll
        for (int kk = 0; kk < 2; ++kk) {
            const int psk = kk * 4 + lk8;
            short8 af[4], bfr[4];
            #pragma unroll
            for (int mf = 0; mf < 4; ++mf) {
                const int row = wm * 64 + mf * 16 + lr;
                af[mf] = *(const short8*)(&As[row * F_BK + ((psk ^ (row & 7)) * 8)]);
            }
            #pragma unroll
            for (int nf = 0; nf < 4; ++nf) {
                const int row = wn * 64 + nf * 16 + lr;
                bfr[nf] = *(const short8*)(&Wsh[row * F_BK + ((psk ^ (row & 7)) * 8)]);
            }
            #pragma unroll
            for (int mf = 0; mf < 4; ++mf)
                #pragma unroll
                for (int nf = 0; nf < 4; ++nf)
                    acc[mf][nf] = __builtin_amdgcn_mfma_f32_16x16x32_bf16(af[mf], bfr[nf], acc[mf][nf], 0, 0, 0);
        }
    }
    #pragma unroll
    for (int nf = 0; nf < 4; ++nf) {
        const int v = v0 + wn * 64 + nf * 16 + lr;
        const float bv = bias[v];
        #pragma unroll
        for (int mf = 0; mf < 4; ++mf) {
            const int mrow = m0 + wm * 64 + mf * 16 + (lane >> 4) * 4;
            #pragma unroll
            for (int j = 0; j < 4; ++j)
                out[(size_t)(mrow + j) * Vc + v] = acc[mf][nf][j] + bv;
        }
    }
}

extern "C" void kernel_launch(void* const* d_in, const int* in_sizes, int n_in,
                              void* d_out, int out_size, void* d_ws, size_t ws_size,
                              hipStream_t stream) {
    const float* x = (const float*)d_in[0];
    const float* y = (const float*)d_in[1];
    const float* W = (const float*)d_in[2];
    const float* b = (const float*)d_in[3];
    float* out = (float*)d_out;

    const size_t w_bytes = (size_t)Vc * Dc * sizeof(unsigned short);  // 1 MB
    if (ws_size >= w_bytes) {
        unsigned short* Wt = (unsigned short*)d_ws;
        cvt_wt<<<dim3((Vc * Dc / 8) / 256), 256, 0, stream>>>(W, Wt);
        joiner_v8<<<dim3((Bc * Tc * Uc / BM) * (Vc / BN)), BDIM, 0, stream>>>(x, y, Wt, b, out);
    } else {
        joiner_mfma<<<dim3(F_MT * F_NT), 256, 0, stream>>>(x, y, W, b, out);
    }
}

// Round 10
// 184.642 us; speedup vs baseline: 1.3089x; 1.0035x over previous
//
#include <hip/hip_runtime.h>
#include <hip/hip_bf16.h>

// RNN-T joiner: out[b,t,u,v] = sum_k relu(x[b,t,k]+y[b,u,k]) * W[v,k] + bias[v]
// GEMM: M=131072, N=1024, K=512; A generated on the fly.
//
// v8 = v6 (best: 201us; barrier-free k-loop, W->regs from L2, A-only 64KB LDS,
// 2 blocks/CU, wave tile 64x64 mfma_32x32x16) + :
//  1) block remap nhalf=blockIdx>>11: co-resident blocks share the same W
//     stream (L1/L2-hot) -> W L2 traffic per CU ~halves.
//  2) A-staging packs bf16 via v_cvt_pk_bf16_f32 (RNE, 2 elems/inst).
//  3) first W prefetch issued before staging (latency hidden under staging).

constexpr int Bc = 8, Tc = 256, Uc = 64, Dc = 512, Vc = 1024;
constexpr int BM = 64, BN = 512;
constexpr int NSTEPS = 16;   // K=512 in steps of 32
constexpr int BDIM = 512;    // 8 waves, side by side in n

typedef __attribute__((ext_vector_type(8)))  short short8;
typedef __attribute__((ext_vector_type(8)))  unsigned short ushort8;
typedef __attribute__((ext_vector_type(4)))  float f32x4;
typedef __attribute__((ext_vector_type(16))) float f32x16;
typedef __attribute__((ext_vector_type(4)))  unsigned int u32x4;

__device__ inline unsigned short f2bf(float f) {
    union { float f; unsigned u; } v; v.f = f;
    unsigned r = v.u + 0x7FFFu + ((v.u >> 16) & 1u);  // RNE
    return (unsigned short)(r >> 16);
}

__device__ inline unsigned int pkbf(float lo, float hi) {
    unsigned int r;
    asm("v_cvt_pk_bf16_f32 %0, %1, %2" : "=v"(r) : "v"(lo), "v"(hi));
    return r;  // lo word = cvt(lo), hi word = cvt(hi), RNE
}

// ---- prep: W fp32 [V][D] -> bf16 chunk layout Wt[(koct>>1)*2048 + v*2 + (koct&1)]
__global__ __launch_bounds__(256) void cvt_wt(const float* __restrict__ W,
                                              unsigned short* __restrict__ Wt) {
    const int idx  = blockIdx.x * 256 + threadIdx.x;  // 65536 total
    const int v    = idx >> 6;
    const int koct = idx & 63;
    const float4 a = *(const float4*)(W + (size_t)v * Dc + koct * 8);
    const float4 b = *(const float4*)(W + (size_t)v * Dc + koct * 8 + 4);
    ushort8 o;
    o[0] = f2bf(a.x); o[1] = f2bf(a.y); o[2] = f2bf(a.z); o[3] = f2bf(a.w);
    o[4] = f2bf(b.x); o[5] = f2bf(b.y); o[6] = f2bf(b.z); o[7] = f2bf(b.w);
    const size_t chunk = (size_t)(koct >> 1) * 2048 + v * 2 + (koct & 1);
    *(ushort8*)(Wt + chunk * 8) = o;
}

__global__ __launch_bounds__(BDIM, 4) void joiner_v8(
    const float* __restrict__ x, const float* __restrict__ y,
    const unsigned short* __restrict__ Wt, const float* __restrict__ bias,
    float* __restrict__ out)
{
    __shared__ __align__(16) unsigned char smem[BM * Dc * 2];  // 64 KB
    unsigned short* As = (unsigned short*)smem;

    const int tid  = threadIdx.x;
    const int lane = tid & 63;
    const int wid  = tid >> 6;        // 0..7, n-position
    const int l31  = lane & 31;
    const int l32  = lane >> 5;       // 0/1

    // co-resident blocks (~256 apart) share nhalf -> shared W stream
    const int nhalf = blockIdx.x >> 11;      // grid = 4096
    const int mb    = blockIdx.x & 2047;
    const int bb    = mb >> 8;               // batch
    const int tt    = mb & 255;              // time step
    const int m0    = mb * BM;
    const int n0    = nhalf * BN;
    const int colbase = n0 + wid * 64;

    float bv[2];
    bv[0] = bias[colbase + l31];
    bv[1] = bias[colbase + 32 + l31];

    // ---- W frag base: chunk (ks*2+q)*2048 + col*2 + l32 ----
    const unsigned short* pW = Wt + (size_t)(colbase * 2 + 2 * l31 + l32) * 8;

    short8 wfA[2][2], wfB[2][2];  // [q][n16] named double-buffer

    #define LOADW(buf, ks)                                                    \
        {                                                                     \
            _Pragma("unroll")                                                 \
            for (int q = 0; q < 2; ++q)                                       \
                _Pragma("unroll")                                             \
                for (int n16 = 0; n16 < 2; ++n16)                             \
                    buf[q][n16] = *(const short8*)(pW + ((ks) * 2 + q) * 16384 \
                                                   + n16 * 512);              \
        }

    LOADW(wfA, 0);   // issued before staging: latency hidden under stage phase

    // ---- stage A = relu(x[b,t,:]+y[b,u,:]) bf16 via cvt_pk, XOR-swizzled ----
    const float* xrow = x + (size_t)(bb * Tc + tt) * Dc;
    #pragma unroll
    for (int i = 0; i < 8; ++i) {
        const int c = tid + i * BDIM;
        const int u = c >> 6;
        const int s = c & 63;
        const float4* xp = (const float4*)(xrow + s * 8);
        const float4* yp = (const float4*)(y + ((size_t)(bb * Uc + u) * Dc + s * 8));
        float4 xa = xp[0], xb = xp[1];
        float4 ya = yp[0], yb = yp[1];
        u32x4 pv;
        pv[0] = pkbf(fmaxf(xa.x + ya.x, 0.f), fmaxf(xa.y + ya.y, 0.f));
        pv[1] = pkbf(fmaxf(xa.z + ya.z, 0.f), fmaxf(xa.w + ya.w, 0.f));
        pv[2] = pkbf(fmaxf(xb.x + yb.x, 0.f), fmaxf(xb.y + yb.y, 0.f));
        pv[3] = pkbf(fmaxf(xb.z + yb.z, 0.f), fmaxf(xb.w + yb.w, 0.f));
        *(u32x4*)(&As[u * Dc + ((s ^ (u & 7)) * 8)]) = pv;
    }
    __syncthreads();

    f32x16 acc[2][2] = {};  // [m16][n16] 32x32 sub-tiles

    #define STEP(cur, nxt, ks)                                                \
        {                                                                     \
            if ((ks) + 1 < NSTEPS) LOADW(nxt, (ks) + 1);                      \
            _Pragma("unroll")                                                 \
            for (int q = 0; q < 2; ++q) {                                     \
                const int oA = (ks) * 4 + q * 2 + l32;                        \
                short8 af0 = *(const short8*)(&As[l31 * Dc                    \
                                              + ((oA ^ (l31 & 7)) * 8)]);     \
                short8 af1 = *(const short8*)(&As[(32 + l31) * Dc             \
                                              + ((oA ^ (l31 & 7)) * 8)]);     \
                __builtin_amdgcn_s_setprio(1);                                \
                acc[0][0] = __builtin_amdgcn_mfma_f32_32x32x16_bf16(          \
                    af0, cur[q][0], acc[0][0], 0, 0, 0);                      \
                acc[0][1] = __builtin_amdgcn_mfma_f32_32x32x16_bf16(          \
                    af0, cur[q][1], acc[0][1], 0, 0, 0);                      \
                acc[1][0] = __builtin_amdgcn_mfma_f32_32x32x16_bf16(          \
                    af1, cur[q][0], acc[1][0], 0, 0, 0);                      \
                acc[1][1] = __builtin_amdgcn_mfma_f32_32x32x16_bf16(          \
                    af1, cur[q][1], acc[1][1], 0, 0, 0);                      \
                __builtin_amdgcn_s_setprio(0);                                \
            }                                                                 \
        }

    #pragma unroll
    for (int ks = 0; ks < NSTEPS; ks += 2) {
        STEP(wfA, wfB, ks);
        STEP(wfB, wfA, ks + 1);
    }
    #undef STEP
    #undef LOADW

    // ---- epilogue: overlay Tr on As space (all A reads done) ----
    __syncthreads();
    float* tr = (float*)smem + wid * (16 * 36);  // 2.3KB per wave
    #pragma unroll
    for (int m16 = 0; m16 < 2; ++m16) {
        #pragma unroll
        for (int n16 = 0; n16 < 2; ++n16) {
            #pragma unroll
            for (int h = 0; h < 2; ++h) {   // regs h*8..h*8+7 -> rows h*16..+15
                #pragma unroll
                for (int e = 0; e < 8; ++e) {
                    const int rl = (e & 3) + 8 * (e >> 2) + 4 * l32;  // 0..15
                    tr[rl * 36 + l31] = acc[m16][n16][h * 8 + e] + bv[n16];
                }
                #pragma unroll
                for (int h2 = 0; h2 < 2; ++h2) {
                    const int rr = h2 * 8 + (lane >> 3);   // 0..15
                    const int c4 = (lane & 7) * 4;         // 0..28
                    f32x4 o;
                    o[0] = tr[rr * 36 + c4 + 0];
                    o[1] = tr[rr * 36 + c4 + 1];
                    o[2] = tr[rr * 36 + c4 + 2];
                    o[3] = tr[rr * 36 + c4 + 3];
                    const size_t off =
                        (size_t)(m0 + m16 * 32 + h * 16 + rr) * Vc
                        + colbase + n16 * 32 + c4;
                    __builtin_nontemporal_store(o, (f32x4*)(out + off));
                }
            }
        }
    }
}

// ---- round-1 fallback (only if ws_size < 1MB) ----
constexpr int F_BM = 128, F_BN = 128, F_BK = 64;
constexpr int F_MT = (Bc * Tc * Uc) / F_BM;
constexpr int F_NT = Vc / F_BN;

__global__ __launch_bounds__(256) void joiner_mfma(
    const float* __restrict__ x, const float* __restrict__ y,
    const float* __restrict__ W, const float* __restrict__ bias,
    float* __restrict__ out)
{
    __shared__ unsigned short As[F_BM * F_BK];
    __shared__ unsigned short Wsh[F_BN * F_BK];
    const int tid = threadIdx.x;
    const int mtile = blockIdx.x % F_MT;
    const int ntile = blockIdx.x / F_MT;
    const int m0 = mtile * F_BM, v0 = ntile * F_BN;
    const int bb = m0 / (Tc * Uc);
    const int t0 = (m0 % (Tc * Uc)) / Uc;
    const int lane = tid & 63, wid = tid >> 6;
    const int wm = wid >> 1, wn = wid & 1;
    const int lr = lane & 15, lk8 = lane >> 4;
    f32x4 acc[4][4] = {};
    for (int k0 = 0; k0 < Dc; k0 += F_BK) {
        __syncthreads();
        #pragma unroll
        for (int i = 0; i < 4; ++i) {
            const int chunk = tid + i * 256;
            const int row = chunk >> 3, slot = chunk & 7;
            const int ps8 = (slot ^ (row & 7)) * 8;
            const int t = t0 + (row >> 6), u = row & 63;
            const float4* xp = (const float4*)(x + ((size_t)(bb * Tc + t) * Dc + k0 + slot * 8));
            const float4* yp = (const float4*)(y + ((size_t)(bb * Uc + u) * Dc + k0 + slot * 8));
            float4 xa = xp[0], xb2 = xp[1], ya = yp[0], yb2 = yp[1];
            ushort8 hv;
            hv[0] = f2bf(fmaxf(xa.x + ya.x, 0.f)); hv[1] = f2bf(fmaxf(xa.y + ya.y, 0.f));
            hv[2] = f2bf(fmaxf(xa.z + ya.z, 0.f)); hv[3] = f2bf(fmaxf(xa.w + ya.w, 0.f));
            hv[4] = f2bf(fmaxf(xb2.x + yb2.x, 0.f)); hv[5] = f2bf(fmaxf(xb2.y + yb2.y, 0.f));
            hv[6] = f2bf(fmaxf(xb2.z + yb2.z, 0.f)); hv[7] = f2bf(fmaxf(xb2.w + yb2.w, 0.f));
            *(ushort8*)(&As[row * F_BK + ps8]) = hv;
            const float4* wp = (const float4*)(W + ((size_t)(v0 + row) * Dc + k0 + slot * 8));
            float4 wa = wp[0], wb2 = wp[1];
            ushort8 wv;
            wv[0] = f2bf(wa.x); wv[1] = f2bf(wa.y); wv[2] = f2bf(wa.z); wv[3] = f2bf(wa.w);
            wv[4] = f2bf(wb2.x); wv[5] = f2bf(wb2.y); wv[6] = f2bf(wb2.z); wv[7] = f2bf(wb2.w);
            *(ushort8*)(&Wsh[row * F_BK + ps8]) = wv;
        }
        __syncthreads();
        #pragma unroll
        for (int kk = 0; kk < 2; ++kk) {
            const int psk = kk * 4 + lk8;
            short8 af[4], bfr[4];
            #pragma unroll
            for (int mf = 0; mf < 4; ++mf) {
                const int row = wm * 64 + mf * 16 + lr;
                af[mf] = *(const short8*)(&As[row * F_BK + ((psk ^ (row & 7)) * 8)]);
            }
            #pragma unroll
            for (int nf = 0; nf < 4; ++nf) {
                const int row = wn * 64 + nf * 16 + lr;
                bfr[nf] = *(const short8*)(&Wsh[row * F_BK + ((psk ^ (row & 7)) * 8)]);
            }
            #pragma unroll
            for (int mf = 0; mf < 4; ++mf)
                #pragma unroll
                for (int nf = 0; nf < 4; ++nf)
                    acc[mf][nf] = __builtin_amdgcn_mfma_f32_16x16x32_bf16(af[mf], bfr[nf], acc[mf][nf], 0, 0, 0);
        }
    }
    #pragma unroll
    for (int nf = 0; nf < 4; ++nf) {
        const int v = v0 + wn * 64 + nf * 16 + lr;
        const float bv = bias[v];
        #pragma unroll
        for (int mf = 0; mf < 4; ++mf) {
            const int mrow = m0 + wm * 64 + mf * 16 + (lane >> 4) * 4;
            #pragma unroll
            for (int j = 0; j < 4; ++j)
                out[(size_t)(mrow + j) * Vc + v] = acc[mf][nf][j] + bv;
        }
    }
}

extern "C" void kernel_launch(void* const* d_in, const int* in_sizes, int n_in,
                              void* d_out, int out_size, void* d_ws, size_t ws_size,
                              hipStream_t stream) {
    const float* x = (const float*)d_in[0];
    const float* y = (const float*)d_in[1];
    const float* W = (const float*)d_in[2];
    const float* b = (const float*)d_in[3];
    float* out = (float*)d_out;

    const size_t w_bytes = (size_t)Vc * Dc * sizeof(unsigned short);  // 1 MB
    if (ws_size >= w_bytes) {
        unsigned short* Wt = (unsigned short*)d_ws;
        cvt_wt<<<dim3((Vc * Dc / 8) / 256), 256, 0, stream>>>(W, Wt);
        joiner_v8<<<dim3((Bc * Tc * Uc / BM) * (Vc / BN)), BDIM, 0, stream>>>(x, y, Wt, b, out);
    } else {
        joiner_mfma<<<dim3(F_MT * F_NT), 256, 0, stream>>>(x, y, W, b, out);
    }
}

// Round 11
// 184.604 us; speedup vs baseline: 1.3091x; 1.0002x over previous
//
#include <hip/hip_runtime.h>
#include <hip/hip_bf16.h>

// RNN-T joiner: out[b,t,u,v] = sum_k relu(x[b,t,k]+y[b,u,k]) * W[v,k] + bias[v]
// GEMM: M=131072, N=1024, K=512; A generated on the fly.
//
// v8 = v6 (best: 201us; barrier-free k-loop, W->regs from L2, A-only 64KB LDS,
// 2 blocks/CU, wave tile 64x64 mfma_32x32x16) + :
//  1) block remap nhalf=blockIdx>>11: co-resident blocks share the same W
//     stream (L1/L2-hot) -> W L2 traffic per CU ~halves.
//  2) A-staging packs bf16 via v_cvt_pk_bf16_f32 (RNE, 2 elems/inst).
//  3) first W prefetch issued before staging (latency hidden under staging).

constexpr int Bc = 8, Tc = 256, Uc = 64, Dc = 512, Vc = 1024;
constexpr int BM = 64, BN = 512;
constexpr int NSTEPS = 16;   // K=512 in steps of 32
constexpr int BDIM = 512;    // 8 waves, side by side in n

typedef __attribute__((ext_vector_type(8)))  short short8;
typedef __attribute__((ext_vector_type(8)))  unsigned short ushort8;
typedef __attribute__((ext_vector_type(4)))  float f32x4;
typedef __attribute__((ext_vector_type(16))) float f32x16;
typedef __attribute__((ext_vector_type(4)))  unsigned int u32x4;

__device__ inline unsigned short f2bf(float f) {
    union { float f; unsigned u; } v; v.f = f;
    unsigned r = v.u + 0x7FFFu + ((v.u >> 16) & 1u);  // RNE
    return (unsigned short)(r >> 16);
}

__device__ inline unsigned int pkbf(float lo, float hi) {
    unsigned int r;
    asm("v_cvt_pk_bf16_f32 %0, %1, %2" : "=v"(r) : "v"(lo), "v"(hi));
    return r;  // lo word = cvt(lo), hi word = cvt(hi), RNE
}

// ---- prep: W fp32 [V][D] -> bf16 chunk layout Wt[(koct>>1)*2048 + v*2 + (koct&1)]
__global__ __launch_bounds__(256) void cvt_wt(const float* __restrict__ W,
                                              unsigned short* __restrict__ Wt) {
    const int idx  = blockIdx.x * 256 + threadIdx.x;  // 65536 total
    const int v    = idx >> 6;
    const int koct = idx & 63;
    const float4 a = *(const float4*)(W + (size_t)v * Dc + koct * 8);
    const float4 b = *(const float4*)(W + (size_t)v * Dc + koct * 8 + 4);
    ushort8 o;
    o[0] = f2bf(a.x); o[1] = f2bf(a.y); o[2] = f2bf(a.z); o[3] = f2bf(a.w);
    o[4] = f2bf(b.x); o[5] = f2bf(b.y); o[6] = f2bf(b.z); o[7] = f2bf(b.w);
    const size_t chunk = (size_t)(koct >> 1) * 2048 + v * 2 + (koct & 1);
    *(ushort8*)(Wt + chunk * 8) = o;
}

__global__ __launch_bounds__(BDIM, 4) void joiner_v8(
    const float* __restrict__ x, const float* __restrict__ y,
    const unsigned short* __restrict__ Wt, const float* __restrict__ bias,
    float* __restrict__ out)
{
    __shared__ __align__(16) unsigned char smem[BM * Dc * 2];  // 64 KB
    unsigned short* As = (unsigned short*)smem;

    const int tid  = threadIdx.x;
    const int lane = tid & 63;
    const int wid  = tid >> 6;        // 0..7, n-position
    const int l31  = lane & 31;
    const int l32  = lane >> 5;       // 0/1

    // co-resident blocks (~256 apart) share nhalf -> shared W stream
    const int nhalf = blockIdx.x >> 11;      // grid = 4096
    const int mb    = blockIdx.x & 2047;
    const int bb    = mb >> 8;               // batch
    const int tt    = mb & 255;              // time step
    const int m0    = mb * BM;
    const int n0    = nhalf * BN;
    const int colbase = n0 + wid * 64;

    float bv[2];
    bv[0] = bias[colbase + l31];
    bv[1] = bias[colbase + 32 + l31];

    // ---- W frag base: chunk (ks*2+q)*2048 + col*2 + l32 ----
    const unsigned short* pW = Wt + (size_t)(colbase * 2 + 2 * l31 + l32) * 8;

    short8 wfA[2][2], wfB[2][2];  // [q][n16] named double-buffer

    #define LOADW(buf, ks)                                                    \
        {                                                                     \
            _Pragma("unroll")                                                 \
            for (int q = 0; q < 2; ++q)                                       \
                _Pragma("unroll")                                             \
                for (int n16 = 0; n16 < 2; ++n16)                             \
                    buf[q][n16] = *(const short8*)(pW + ((ks) * 2 + q) * 16384 \
                                                   + n16 * 512);              \
        }

    LOADW(wfA, 0);   // issued before staging: latency hidden under stage phase

    // ---- stage A = relu(x[b,t,:]+y[b,u,:]) bf16 via cvt_pk, XOR-swizzled ----
    const float* xrow = x + (size_t)(bb * Tc + tt) * Dc;
    #pragma unroll
    for (int i = 0; i < 8; ++i) {
        const int c = tid + i * BDIM;
        const int u = c >> 6;
        const int s = c & 63;
        const float4* xp = (const float4*)(xrow + s * 8);
        const float4* yp = (const float4*)(y + ((size_t)(bb * Uc + u) * Dc + s * 8));
        float4 xa = xp[0], xb = xp[1];
        float4 ya = yp[0], yb = yp[1];
        u32x4 pv;
        pv[0] = pkbf(fmaxf(xa.x + ya.x, 0.f), fmaxf(xa.y + ya.y, 0.f));
        pv[1] = pkbf(fmaxf(xa.z + ya.z, 0.f), fmaxf(xa.w + ya.w, 0.f));
        pv[2] = pkbf(fmaxf(xb.x + yb.x, 0.f), fmaxf(xb.y + yb.y, 0.f));
        pv[3] = pkbf(fmaxf(xb.z + yb.z, 0.f), fmaxf(xb.w + yb.w, 0.f));
        *(u32x4*)(&As[u * Dc + ((s ^ (u & 7)) * 8)]) = pv;
    }
    __syncthreads();

    f32x16 acc[2][2] = {};  // [m16][n16] 32x32 sub-tiles

    #define STEP(cur, nxt, ks)                                                \
        {                                                                     \
            if ((ks) + 1 < NSTEPS) LOADW(nxt, (ks) + 1);                      \
            _Pragma("unroll")                                                 \
            for (int q = 0; q < 2; ++q) {                                     \
                const int oA = (ks) * 4 + q * 2 + l32;                        \
                short8 af0 = *(const short8*)(&As[l31 * Dc                    \
                                              + ((oA ^ (l31 & 7)) * 8)]);     \
                short8 af1 = *(const short8*)(&As[(32 + l31) * Dc             \
                                              + ((oA ^ (l31 & 7)) * 8)]);     \
                __builtin_amdgcn_s_setprio(1);                                \
                acc[0][0] = __builtin_amdgcn_mfma_f32_32x32x16_bf16(          \
                    af0, cur[q][0], acc[0][0], 0, 0, 0);                      \
                acc[0][1] = __builtin_amdgcn_mfma_f32_32x32x16_bf16(          \
                    af0, cur[q][1], acc[0][1], 0, 0, 0);                      \
                acc[1][0] = __builtin_amdgcn_mfma_f32_32x32x16_bf16(          \
                    af1, cur[q][0], acc[1][0], 0, 0, 0);                      \
                acc[1][1] = __builtin_amdgcn_mfma_f32_32x32x16_bf16(          \
                    af1, cur[q][1], acc[1][1], 0, 0, 0);                      \
                __builtin_amdgcn_s_setprio(0);                                \
            }                                                                 \
        }

    #pragma unroll
    for (int ks = 0; ks < NSTEPS; ks += 2) {
        STEP(wfA, wfB, ks);
        STEP(wfB, wfA, ks + 1);
    }
    #undef STEP
    #undef LOADW

    // ---- epilogue: overlay Tr on As space (all A reads done) ----
    __syncthreads();
    float* tr = (float*)smem + wid * (16 * 36);  // 2.3KB per wave
    #pragma unroll
    for (int m16 = 0; m16 < 2; ++m16) {
        #pragma unroll
        for (int n16 = 0; n16 < 2; ++n16) {
            #pragma unroll
            for (int h = 0; h < 2; ++h) {   // regs h*8..h*8+7 -> rows h*16..+15
                #pragma unroll
                for (int e = 0; e < 8; ++e) {
                    const int rl = (e & 3) + 8 * (e >> 2) + 4 * l32;  // 0..15
                    tr[rl * 36 + l31] = acc[m16][n16][h * 8 + e] + bv[n16];
                }
                #pragma unroll
                for (int h2 = 0; h2 < 2; ++h2) {
                    const int rr = h2 * 8 + (lane >> 3);   // 0..15
                    const int c4 = (lane & 7) * 4;         // 0..28
                    f32x4 o;
                    o[0] = tr[rr * 36 + c4 + 0];
                    o[1] = tr[rr * 36 + c4 + 1];
                    o[2] = tr[rr * 36 + c4 + 2];
                    o[3] = tr[rr * 36 + c4 + 3];
                    const size_t off =
                        (size_t)(m0 + m16 * 32 + h * 16 + rr) * Vc
                        + colbase + n16 * 32 + c4;
                    __builtin_nontemporal_store(o, (f32x4*)(out + off));
                }
            }
        }
    }
}

// ---- round-1 fallback (only if ws_size < 1MB) ----
constexpr int F_BM = 128, F_BN = 128, F_BK = 64;
constexpr int F_MT = (Bc * Tc * Uc) / F_BM;
constexpr int F_NT = Vc / F_BN;

__global__ __launch_bounds__(256) void joiner_mfma(
    const float* __restrict__ x, const float* __restrict__ y,
    const float* __restrict__ W, const float* __restrict__ bias,
    float* __restrict__ out)
{
    __shared__ unsigned short As[F_BM * F_BK];
    __shared__ unsigned short Wsh[F_BN * F_BK];
    const int tid = threadIdx.x;
    const int mtile = blockIdx.x % F_MT;
    const int ntile = blockIdx.x / F_MT;
    const int m0 = mtile * F_BM, v0 = ntile * F_BN;
    const int bb = m0 / (Tc * Uc);
    const int t0 = (m0 % (Tc * Uc)) / Uc;
    const int lane = tid & 63, wid = tid >> 6;
    const int wm = wid >> 1, wn = wid & 1;
    const int lr = lane & 15, lk8 = lane >> 4;
    f32x4 acc[4][4] = {};
    for (int k0 = 0; k0 < Dc; k0 += F_BK) {
        __syncthreads();
        #pragma unroll
        for (int i = 0; i < 4; ++i) {
            const int chunk = tid + i * 256;
            const int row = chunk >> 3, slot = chunk & 7;
            const int ps8 = (slot ^ (row & 7)) * 8;
            const int t = t0 + (row >> 6), u = row & 63;
            const float4* xp = (const float4*)(x + ((size_t)(bb * Tc + t) * Dc + k0 + slot * 8));
            const float4* yp = (const float4*)(y + ((size_t)(bb * Uc + u) * Dc + k0 + slot * 8));
            float4 xa = xp[0], xb2 = xp[1], ya = yp[0], yb2 = yp[1];
            ushort8 hv;
            hv[0] = f2bf(fmaxf(xa.x + ya.x, 0.f)); hv[1] = f2bf(fmaxf(xa.y + ya.y, 0.f));
            hv[2] = f2bf(fmaxf(xa.z + ya.z, 0.f)); hv[3] = f2bf(fmaxf(xa.w + ya.w, 0.f));
            hv[4] = f2bf(fmaxf(xb2.x + yb2.x, 0.f)); hv[5] = f2bf(fmaxf(xb2.y + yb2.y, 0.f));
            hv[6] = f2bf(fmaxf(xb2.z + yb2.z, 0.f)); hv[7] = f2bf(fmaxf(xb2.w + yb2.w, 0.f));
            *(ushort8*)(&As[row * F_BK + ps8]) = hv;
            const float4* wp = (const float4*)(W + ((size_t)(v0 + row) * Dc + k0 + slot * 8));
            float4 wa = wp[0], wb2 = wp[1];
            ushort8 wv;
            wv[0] = f2bf(wa.x); wv[1] = f2bf(wa.y); wv[2] = f2bf(wa.z); wv[3] = f2bf(wa.w);
            wv[4] = f2bf(wb2.x); wv[5] = f2bf(wb2.y); wv[6] = f2bf(wb2.z); wv[7] = f2bf(wb2.w);
            *(ushort8*)(&Wsh[row * F_BK + ps8]) = wv;
        }
        __syncthreads();
        #pragma unroll
        for (int kk = 0; kk < 2; ++kk) {
            const int psk = kk * 4 + lk8;
            short8 af[4], bfr[4];
            #pragma unroll
            for (int mf = 0; mf < 4; ++mf) {
                const int row = wm * 64 + mf * 16 + lr;
                af[mf] = *(const short8*)(&As[row * F_BK + ((psk ^ (row & 7)) * 8)]);
            }
            #pragma unroll
            for (int nf = 0; nf < 4; ++nf) {
                const int row = wn * 64 + nf * 16 + lr;
                bfr[nf] = *(const short8*)(&Wsh[row * F_BK + ((psk ^ (row & 7)) * 8)]);
            }
            #pragma unroll
            for (int mf = 0; mf < 4; ++mf)
                #pragma unroll
                for (int nf = 0; nf < 4; ++nf)
                    acc[mf][nf] = __builtin_amdgcn_mfma_f32_16x16x32_bf16(af[mf], bfr[nf], acc[mf][nf], 0, 0, 0);
        }
    }
    #pragma unroll
    for (int nf = 0; nf < 4; ++nf) {
        const int v = v0 + wn * 64 + nf * 16 + lr;
        const float bv = bias[v];
        #pragma unroll
        for (int mf = 0; mf < 4; ++mf) {
            const int mrow = m0 + wm * 64 + mf * 16 + (lane >> 4) * 4;
            #pragma unroll
            for (int j = 0; j < 4; ++j)
                out[(size_t)(mrow + j) * Vc + v] = acc[mf][nf][j] + bv;
        }
    }
}

extern "C" void kernel_launch(void* const* d_in, const int* in_sizes, int n_in,
                              void* d_out, int out_size, void* d_ws, size_t ws_size,
                              hipStream_t stream) {
    const float* x = (const float*)d_in[0];
    const float* y = (const float*)d_in[1];
    const float* W = (const float*)d_in[2];
    const float* b = (const float*)d_in[3];
    float* out = (float*)d_out;

    const size_t w_bytes = (size_t)Vc * Dc * sizeof(unsigned short);  // 1 MB
    if (ws_size >= w_bytes) {
        unsigned short* Wt = (unsigned short*)d_ws;
        cvt_wt<<<dim3((Vc * Dc / 8) / 256), 256, 0, stream>>>(W, Wt);
        joiner_v8<<<dim3((Bc * Tc * Uc / BM) * (Vc / BN)), BDIM, 0, stream>>>(x, y, Wt, b, out);
    } else {
        joiner_mfma<<<dim3(F_MT * F_NT), 256, 0, stream>>>(x, y, W, b, out);
    }
}